// Round 1
// baseline (892.097 us; speedup 1.0000x reference)
//
#include <hip/hip_runtime.h>
#include <math.h>

// ---------------------------------------------------------------------------
// Problem constants
//   DIM=256 HEADS=16 DHEAD=16 H=12 W=26 (HW=312)  Hk=3 Wk=6 (J=18)  B=256
//   q_map[b,c,s] = q[b, (c*312+s)%256] = q[b,(c*56+s)&255]  (tile/reshape quirk)
// ---------------------------------------------------------------------------

// workspace layout (floats)
#define WS_GKV 0              // [256][18][2]   grid_kv (n0,n1)
#define WS_K   9216           // [256][256][18] k
#define WS_V   1188864        // [256][256][18] v
#define WS_WA  2368512        // [256][16][18]  wA = sum_i conv_w[i]*attn[...]
#define WS_WA_BYTES (73728u * 4u)

// ===========================================================================
// K1: per-batch preprocessing: depthwise conv + GELU -> offsets -> grid ->
//     bilinear sample kv -> k/v 1x1 projections
// ===========================================================================
__global__ __launch_bounds__(256) void k1_prep(
    const float* __restrict__ x, const float* __restrict__ q,
    const float* __restrict__ w_dw, const float* __restrict__ b_dw,
    const float* __restrict__ w_pw,
    const float* __restrict__ wk, const float* __restrict__ wv,
    float* __restrict__ ws)
{
    const int b = blockIdx.x, tid = threadIdx.x;
    __shared__ float q_s[256];
    __shared__ float t_s[18 * 256];        // [p][c]
    __shared__ float off_s[36];            // [o=2][p=18]
    __shared__ float sx0[18], sy0[18], swx[18], swy[18];
    __shared__ float kv_s[256 * 20];       // [c][p] padded 18->20 (float4-able)

    q_s[tid] = q[b * 256 + tid];
    __syncthreads();

    // depthwise 6x6, stride 4, pad 1, + bias, exact GELU.  thread = channel c
    {
        const int c = tid;
        const int cbase = (c * 56) & 255;
        for (int p = 0; p < 18; ++p) {
            const int jh = p / 6, jw = p % 6;
            float acc = b_dw[c];
            for (int kh = 0; kh < 6; ++kh) {
                const int ih = jh * 4 - 1 + kh;
                if (ih < 0 || ih >= 12) continue;
                for (int kw = 0; kw < 6; ++kw) {
                    const int iw = jw * 4 - 1 + kw;
                    if (iw < 0 || iw >= 26) continue;
                    acc += w_dw[c * 36 + kh * 6 + kw] * q_s[(cbase + ih * 26 + iw) & 255];
                }
            }
            t_s[p * 256 + c] = 0.5f * acc * (1.0f + erff(acc * 0.70710678118654752f));
        }
    }
    __syncthreads();

    // offsets: 36 dot-products over 256 channels; wave w handles 9 outputs
    {
        const int wid = tid >> 6, lane = tid & 63;
        for (int r = 0; r < 9; ++r) {
            const int oi = wid * 9 + r;
            const int o = oi / 18, p = oi % 18;
            float s = 0.f;
            for (int c = lane; c < 256; c += 64)
                s += w_pw[o * 256 + c] * t_s[p * 256 + c];
            for (int d = 32; d > 0; d >>= 1) s += __shfl_down(s, d, 64);
            if (lane == 0) off_s[oi] = 4.0f * tanhf(s);
        }
    }
    __syncthreads();

    // grid coords + bilinear sample params
    if (tid < 18) {
        const int j = tid, jh = j / 6, jw = j % 6;
        const float vg0 = (float)jw + off_s[0 * 18 + j];   // x-ish
        const float vg1 = (float)jh + off_s[1 * 18 + j];   // y-ish
        const float n0 = 2.0f * vg0 / 2.0f - 1.0f;         // /(Hk-1)  (repo quirk)
        const float n1 = 2.0f * vg1 / 5.0f - 1.0f;         // /(Wk-1)
        ws[WS_GKV + b * 36 + j * 2 + 0] = n0;
        ws[WS_GKV + b * 36 + j * 2 + 1] = n1;
        const float xp = ((n0 + 1.0f) * 26.0f - 1.0f) * 0.5f;
        const float yp = ((n1 + 1.0f) * 12.0f - 1.0f) * 0.5f;
        const float x0 = floorf(xp), y0 = floorf(yp);
        sx0[j] = x0; sy0[j] = y0; swx[j] = xp - x0; swy[j] = yp - y0;
    }
    __syncthreads();

    // bilinear sample (zero padding).  thread = channel c
    {
        const int c = tid;
        const float* xb = x + ((size_t)b * 256 + c) * 312;
        for (int j = 0; j < 18; ++j) {
            const int x0 = (int)sx0[j], y0 = (int)sy0[j];
            const int x1 = x0 + 1, y1 = y0 + 1;
            const float wx1 = swx[j], wy1 = swy[j];
            const float wx0 = 1.f - wx1, wy0 = 1.f - wy1;
            const bool xv0 = (x0 >= 0) & (x0 < 26), xv1 = (x1 >= 0) & (x1 < 26);
            const bool yv0 = (y0 >= 0) & (y0 < 12), yv1 = (y1 >= 0) & (y1 < 12);
            float v00 = (xv0 & yv0) ? xb[y0 * 26 + x0] : 0.f;
            float v01 = (xv1 & yv0) ? xb[y0 * 26 + x1] : 0.f;
            float v10 = (xv0 & yv1) ? xb[y1 * 26 + x0] : 0.f;
            float v11 = (xv1 & yv1) ? xb[y1 * 26 + x1] : 0.f;
            kv_s[c * 20 + j] = wy0 * (wx0 * v00 + wx1 * v01) + wy1 * (wx0 * v10 + wx1 * v11);
        }
        kv_s[c * 20 + 18] = 0.f; kv_s[c * 20 + 19] = 0.f;
    }
    __syncthreads();

    // k/v projection: thread = output row o; 18+18 outputs per thread
    {
        const int o = tid;
        float ak[20], av[20];
        #pragma unroll
        for (int p = 0; p < 20; ++p) { ak[p] = 0.f; av[p] = 0.f; }
        const float4* wk4 = (const float4*)(wk + o * 256);
        const float4* wv4 = (const float4*)(wv + o * 256);
        for (int c4 = 0; c4 < 64; ++c4) {
            const float4 a4 = wk4[c4];
            const float4 b4 = wv4[c4];
            const float wa[4] = {a4.x, a4.y, a4.z, a4.w};
            const float wb[4] = {b4.x, b4.y, b4.z, b4.w};
            #pragma unroll
            for (int u = 0; u < 4; ++u) {
                const float4* kr = (const float4*)&kv_s[(c4 * 4 + u) * 20];
                #pragma unroll
                for (int p4 = 0; p4 < 5; ++p4) {
                    const float4 kq = kr[p4];
                    ak[p4 * 4 + 0] += wa[u] * kq.x; av[p4 * 4 + 0] += wb[u] * kq.x;
                    ak[p4 * 4 + 1] += wa[u] * kq.y; av[p4 * 4 + 1] += wb[u] * kq.y;
                    ak[p4 * 4 + 2] += wa[u] * kq.z; av[p4 * 4 + 2] += wb[u] * kq.z;
                    ak[p4 * 4 + 3] += wa[u] * kq.w; av[p4 * 4 + 3] += wb[u] * kq.w;
                }
            }
        }
        float* ko = ws + WS_K + (size_t)b * 4608 + o * 18;
        float* vo = ws + WS_V + (size_t)b * 4608 + o * 18;
        #pragma unroll
        for (int p = 0; p < 18; ++p) { ko[p] = ak[p]; vo[p] = av[p]; }
    }
}

// ===========================================================================
// K2: CPB MLP + sim + softmax + conv1d-weighted attention accumulation (wA)
//     grid (39 i-tiles of 8, 256 batches), block 192; thread = one (i,j) pair
// ===========================================================================
__global__ __launch_bounds__(192) void k2_attn(
    const float* __restrict__ q,
    const float* __restrict__ cw1, const float* __restrict__ cb1,
    const float* __restrict__ cw2, const float* __restrict__ cb2,
    const float* __restrict__ cw3, const float* __restrict__ cb3,
    const float* __restrict__ conv_w,
    float* __restrict__ ws)
{
    const int bx = blockIdx.x;        // i-tile (8 i's), 39*8 = 312
    const int b  = blockIdx.y;
    const int tid = threadIdx.x;

    __shared__ float q_s[256];
    __shared__ float k_s[4608];       // [c][j]
    __shared__ float w2_s[4096];      // [k][c]
    __shared__ float w1_s[128], b1_s[64], b2_s[64];
    __shared__ float w3_s[1024];      // [h][k]
    __shared__ float b3_s[16];
    __shared__ float gkv_s[36];
    __shared__ float eb[8 * 288];     // [il][j][h]: logits then exp
    __shared__ float rsum[128];       // [il][h]

    for (int i = tid; i < 256; i += 192) q_s[i] = q[b * 256 + i];
    const float* kb = ws + WS_K + (size_t)b * 4608;
    for (int i = tid; i < 4608; i += 192) k_s[i] = kb[i];
    for (int i = tid; i < 4096; i += 192) w2_s[i] = cw2[i];
    for (int i = tid; i < 1024; i += 192) w3_s[i] = cw3[i];
    if (tid < 128) w1_s[tid] = cw1[tid];
    if (tid < 64) { b1_s[tid] = cb1[tid]; b2_s[tid] = cb2[tid]; }
    if (tid < 16) b3_s[tid] = cb3[tid];
    if (tid < 36) gkv_s[tid] = ws[WS_GKV + b * 36 + tid];
    __syncthreads();

    if (tid < 144) {
        const int il = tid / 18, j = tid % 18;
        const int i = bx * 8 + il;
        const float gq0 = 2.0f * (float)(i % 26) / 11.0f - 1.0f;  // /(H-1) quirk
        const float gq1 = 2.0f * (float)(i / 26) / 25.0f - 1.0f;  // /(W-1) quirk
        const float p0 = gq0 - gkv_s[j * 2 + 0];
        const float p1 = gq1 - gkv_s[j * 2 + 1];
        const float f0 = copysignf(log1pf(fabsf(p0)), p0);
        const float f1 = copysignf(log1pf(fabsf(p1)), p1);

        float h1[64];
        #pragma unroll
        for (int k = 0; k < 64; ++k)
            h1[k] = fmaxf(w1_s[k * 2] * f0 + w1_s[k * 2 + 1] * f1 + b1_s[k], 0.f);

        float b16[16];
        #pragma unroll
        for (int h = 0; h < 16; ++h) b16[h] = b3_s[h];

        // layer2 + fused layer3 (h2 never stored)
        for (int k = 0; k < 64; ++k) {
            float acc0 = b2_s[k], acc1 = 0.f;
            const float4* w2r = (const float4*)&w2_s[k * 64];
            #pragma unroll
            for (int c4 = 0; c4 < 16; c4 += 2) {
                const float4 wa = w2r[c4];
                const float4 wb = w2r[c4 + 1];
                acc0 += h1[c4*4+0]*wa.x + h1[c4*4+1]*wa.y + h1[c4*4+2]*wa.z + h1[c4*4+3]*wa.w;
                acc1 += h1[c4*4+4]*wb.x + h1[c4*4+5]*wb.y + h1[c4*4+6]*wb.z + h1[c4*4+7]*wb.w;
            }
            const float l2 = fmaxf(acc0 + acc1, 0.f);
            #pragma unroll
            for (int h = 0; h < 16; ++h) b16[h] += l2 * w3_s[h * 64 + k];
        }

        // sim[h] + bias -> logits
        #pragma unroll 1
        for (int h = 0; h < 16; ++h) {
            float s = 0.f;
            #pragma unroll
            for (int d = 0; d < 16; ++d) {
                const int c = h * 16 + d;
                s += q_s[(c * 56 + i) & 255] * k_s[c * 18 + j];
            }
            eb[il * 288 + j * 16 + h] = 0.25f * s + b16[h];
        }
    }
    __syncthreads();

    // softmax over j per (il, h)
    if (tid < 128) {
        const int il = tid >> 4, h = tid & 15;
        const int base = il * 288 + h;
        float m = -1e30f;
        for (int j = 0; j < 18; ++j) m = fmaxf(m, eb[base + j * 16]);
        float s = 0.f;
        for (int j = 0; j < 18; ++j) {
            const float e = expf(eb[base + j * 16] - m);
            eb[base + j * 16] = e;
            s += e;
        }
        rsum[tid] = 1.0f / s;
    }
    __syncthreads();

    // wA[b,h,j] += sum_il conv_w[i] * attn
    for (int t = tid; t < 288; t += 192) {
        const int h = t / 18, j = t % 18;
        float acc = 0.f;
        for (int il = 0; il < 8; ++il)
            acc += conv_w[bx * 8 + il] * eb[il * 288 + j * 16 + h] * rsum[il * 16 + h];
        atomicAdd(&ws[WS_WA + b * 288 + h * 18 + j], acc);
    }
}

// ===========================================================================
// K3: m = wA . v ; pooled = w_out.m + b_out*S + conv_b ; +q ; LayerNorm
// ===========================================================================
__global__ __launch_bounds__(256) void k3_final(
    const float* __restrict__ q,
    const float* __restrict__ w_out, const float* __restrict__ b_out,
    const float* __restrict__ conv_w, const float* __restrict__ conv_b,
    const float* __restrict__ ln_g, const float* __restrict__ ln_b,
    const float* __restrict__ ws, float* __restrict__ out)
{
    const int b = blockIdx.x, tid = threadIdx.x;
    __shared__ float wA_s[288];
    __shared__ float m_s[256];
    __shared__ float redS[4], redA[4], redB[4];

    for (int i = tid; i < 288; i += 256) wA_s[i] = ws[WS_WA + b * 288 + i];
    __syncthreads();

    // m[c] = sum_j wA[c>>4, j] * v[c, j]
    {
        const int c = tid;
        const float* vr = ws + WS_V + (size_t)b * 4608 + c * 18;
        const float* wr = &wA_s[(c >> 4) * 18];
        float acc = 0.f;
        #pragma unroll
        for (int j = 0; j < 18; ++j) acc += wr[j] * vr[j];
        m_s[c] = acc;
    }
    // S = sum conv_w
    {
        float sp = conv_w[tid] + ((tid + 256) < 312 ? conv_w[tid + 256] : 0.f);
        for (int d = 32; d > 0; d >>= 1) sp += __shfl_down(sp, d, 64);
        if ((tid & 63) == 0) redS[tid >> 6] = sp;
    }
    __syncthreads();
    const float S = redS[0] + redS[1] + redS[2] + redS[3];

    const int o = tid;
    float acc = b_out[o] * S + conv_b[0];
    const float4* wor = (const float4*)(w_out + o * 256);
    const float4* m4 = (const float4*)m_s;
    for (int c4 = 0; c4 < 64; ++c4) {
        const float4 wq = wor[c4];
        const float4 mq = m4[c4];
        acc += wq.x * mq.x + wq.y * mq.y + wq.z * mq.z + wq.w * mq.w;
    }
    const float y = acc + q[b * 256 + o];

    // LayerNorm over 256
    float s1 = y, s2 = y * y;
    for (int d = 32; d > 0; d >>= 1) {
        s1 += __shfl_down(s1, d, 64);
        s2 += __shfl_down(s2, d, 64);
    }
    if ((tid & 63) == 0) { redA[tid >> 6] = s1; redB[tid >> 6] = s2; }
    __syncthreads();
    const float S1 = redA[0] + redA[1] + redA[2] + redA[3];
    const float S2 = redB[0] + redB[1] + redB[2] + redB[3];
    const float mu = S1 * (1.0f / 256.0f);
    const float var = S2 * (1.0f / 256.0f) - mu * mu;
    out[b * 256 + o] = (y - mu) * rsqrtf(var + 1e-5f) * ln_g[o] + ln_b[o];
}

// ===========================================================================
extern "C" void kernel_launch(void* const* d_in, const int* in_sizes, int n_in,
                              void* d_out, int out_size, void* d_ws, size_t ws_size,
                              hipStream_t stream) {
    const float* x       = (const float*)d_in[0];
    const float* q       = (const float*)d_in[1];
    const float* w_dw    = (const float*)d_in[2];
    const float* b_dw    = (const float*)d_in[3];
    const float* w_pw    = (const float*)d_in[4];
    const float* wk      = (const float*)d_in[5];
    const float* wv      = (const float*)d_in[6];
    const float* w_out   = (const float*)d_in[7];
    const float* b_out   = (const float*)d_in[8];
    const float* cw1     = (const float*)d_in[9];
    const float* cb1     = (const float*)d_in[10];
    const float* cw2     = (const float*)d_in[11];
    const float* cb2     = (const float*)d_in[12];
    const float* cw3     = (const float*)d_in[13];
    const float* cb3     = (const float*)d_in[14];
    const float* conv_w  = (const float*)d_in[15];
    const float* conv_b  = (const float*)d_in[16];
    const float* ln_g    = (const float*)d_in[17];
    const float* ln_b    = (const float*)d_in[18];
    float* ws = (float*)d_ws;
    float* out = (float*)d_out;

    hipMemsetAsync((char*)d_ws + (size_t)WS_WA * sizeof(float), 0, WS_WA_BYTES, stream);
    k1_prep<<<256, 256, 0, stream>>>(x, q, w_dw, b_dw, w_pw, wk, wv, ws);
    k2_attn<<<dim3(39, 256), 192, 0, stream>>>(q, cw1, cb1, cw2, cb2, cw3, cb3, conv_w, ws);
    k3_final<<<256, 256, 0, stream>>>(q, w_out, b_out, conv_w, conv_b, ln_g, ln_b, ws, out);
}

// Round 2
// 338.450 us; speedup vs baseline: 2.6358x; 2.6358x over previous
//
#include <hip/hip_runtime.h>
#include <math.h>

// ---------------------------------------------------------------------------
// DIM=256 HEADS=16 DHEAD=16 H=12 W=26 (HW=312)  Hk=3 Wk=6 (J=18)  B=256
// q_map[b,c,s] = q[b,(c*56+s)&255]
// ---------------------------------------------------------------------------

// workspace layout (floats)
#define WS_GKV 0              // [256][18][2]   grid_kv (n0,n1)
#define WS_K   9216           // [256][256][18] k
#define WS_V   1188864        // [256][256][18] v
#define WS_WA  2368512        // [256][16][18]  wA = sum_i conv_w[i]*attn
#define WS_WA_BYTES (73728u * 4u)

typedef __attribute__((ext_vector_type(8))) short short8;   // 8 bf16 (guide §3)
typedef __attribute__((ext_vector_type(4))) float floatx4;

union U16 { uint4 u; short8 s; };

__device__ __forceinline__ unsigned short f2bf(float f) {   // RNE f32->bf16
    unsigned int u = __float_as_uint(f);
    u += 0x7fffu + ((u >> 16) & 1u);
    return (unsigned short)(u >> 16);
}
__device__ __forceinline__ short8 pack8(floatx4 a, floatx4 b) {
    short8 r;
    r[0]=(short)f2bf(a[0]); r[1]=(short)f2bf(a[1]); r[2]=(short)f2bf(a[2]); r[3]=(short)f2bf(a[3]);
    r[4]=(short)f2bf(b[0]); r[5]=(short)f2bf(b[1]); r[6]=(short)f2bf(b[2]); r[7]=(short)f2bf(b[3]);
    return r;
}

// ===========================================================================
// K1: per-batch preprocessing (unchanged from round 1)
// ===========================================================================
__global__ __launch_bounds__(256) void k1_prep(
    const float* __restrict__ x, const float* __restrict__ q,
    const float* __restrict__ w_dw, const float* __restrict__ b_dw,
    const float* __restrict__ w_pw,
    const float* __restrict__ wk, const float* __restrict__ wv,
    float* __restrict__ ws)
{
    const int b = blockIdx.x, tid = threadIdx.x;
    __shared__ float q_s[256];
    __shared__ float t_s[18 * 256];
    __shared__ float off_s[36];
    __shared__ float sx0[18], sy0[18], swx[18], swy[18];
    __shared__ float kv_s[256 * 20];

    q_s[tid] = q[b * 256 + tid];
    __syncthreads();

    {
        const int c = tid;
        const int cbase = (c * 56) & 255;
        for (int p = 0; p < 18; ++p) {
            const int jh = p / 6, jw = p % 6;
            float acc = b_dw[c];
            for (int kh = 0; kh < 6; ++kh) {
                const int ih = jh * 4 - 1 + kh;
                if (ih < 0 || ih >= 12) continue;
                for (int kw = 0; kw < 6; ++kw) {
                    const int iw = jw * 4 - 1 + kw;
                    if (iw < 0 || iw >= 26) continue;
                    acc += w_dw[c * 36 + kh * 6 + kw] * q_s[(cbase + ih * 26 + iw) & 255];
                }
            }
            t_s[p * 256 + c] = 0.5f * acc * (1.0f + erff(acc * 0.70710678118654752f));
        }
    }
    __syncthreads();

    {
        const int wid = tid >> 6, lane = tid & 63;
        for (int r = 0; r < 9; ++r) {
            const int oi = wid * 9 + r;
            const int o = oi / 18, p = oi % 18;
            float s = 0.f;
            for (int c = lane; c < 256; c += 64)
                s += w_pw[o * 256 + c] * t_s[p * 256 + c];
            for (int d = 32; d > 0; d >>= 1) s += __shfl_down(s, d, 64);
            if (lane == 0) off_s[oi] = 4.0f * tanhf(s);
        }
    }
    __syncthreads();

    if (tid < 18) {
        const int j = tid, jh = j / 6, jw = j % 6;
        const float vg0 = (float)jw + off_s[0 * 18 + j];
        const float vg1 = (float)jh + off_s[1 * 18 + j];
        const float n0 = 2.0f * vg0 / 2.0f - 1.0f;
        const float n1 = 2.0f * vg1 / 5.0f - 1.0f;
        ws[WS_GKV + b * 36 + j * 2 + 0] = n0;
        ws[WS_GKV + b * 36 + j * 2 + 1] = n1;
        const float xp = ((n0 + 1.0f) * 26.0f - 1.0f) * 0.5f;
        const float yp = ((n1 + 1.0f) * 12.0f - 1.0f) * 0.5f;
        const float x0 = floorf(xp), y0 = floorf(yp);
        sx0[j] = x0; sy0[j] = y0; swx[j] = xp - x0; swy[j] = yp - y0;
    }
    __syncthreads();

    {
        const int c = tid;
        const float* xb = x + ((size_t)b * 256 + c) * 312;
        for (int j = 0; j < 18; ++j) {
            const int x0 = (int)sx0[j], y0 = (int)sy0[j];
            const int x1 = x0 + 1, y1 = y0 + 1;
            const float wx1 = swx[j], wy1 = swy[j];
            const float wx0 = 1.f - wx1, wy0 = 1.f - wy1;
            const bool xv0 = (x0 >= 0) & (x0 < 26), xv1 = (x1 >= 0) & (x1 < 26);
            const bool yv0 = (y0 >= 0) & (y0 < 12), yv1 = (y1 >= 0) & (y1 < 12);
            float v00 = (xv0 & yv0) ? xb[y0 * 26 + x0] : 0.f;
            float v01 = (xv1 & yv0) ? xb[y0 * 26 + x1] : 0.f;
            float v10 = (xv0 & yv1) ? xb[y1 * 26 + x0] : 0.f;
            float v11 = (xv1 & yv1) ? xb[y1 * 26 + x1] : 0.f;
            kv_s[c * 20 + j] = wy0 * (wx0 * v00 + wx1 * v01) + wy1 * (wx0 * v10 + wx1 * v11);
        }
        kv_s[c * 20 + 18] = 0.f; kv_s[c * 20 + 19] = 0.f;
    }
    __syncthreads();

    {
        const int o = tid;
        float ak[20], av[20];
        #pragma unroll
        for (int p = 0; p < 20; ++p) { ak[p] = 0.f; av[p] = 0.f; }
        const float4* wk4 = (const float4*)(wk + o * 256);
        const float4* wv4 = (const float4*)(wv + o * 256);
        for (int c4 = 0; c4 < 64; ++c4) {
            const float4 a4 = wk4[c4];
            const float4 b4 = wv4[c4];
            const float wa[4] = {a4.x, a4.y, a4.z, a4.w};
            const float wb[4] = {b4.x, b4.y, b4.z, b4.w};
            #pragma unroll
            for (int u = 0; u < 4; ++u) {
                const float4* kr = (const float4*)&kv_s[(c4 * 4 + u) * 20];
                #pragma unroll
                for (int p4 = 0; p4 < 5; ++p4) {
                    const float4 kq = kr[p4];
                    ak[p4 * 4 + 0] += wa[u] * kq.x; av[p4 * 4 + 0] += wb[u] * kq.x;
                    ak[p4 * 4 + 1] += wa[u] * kq.y; av[p4 * 4 + 1] += wb[u] * kq.y;
                    ak[p4 * 4 + 2] += wa[u] * kq.z; av[p4 * 4 + 2] += wb[u] * kq.z;
                    ak[p4 * 4 + 3] += wa[u] * kq.w; av[p4 * 4 + 3] += wb[u] * kq.w;
                }
            }
        }
        float* ko = ws + WS_K + (size_t)b * 4608 + o * 18;
        float* vo = ws + WS_V + (size_t)b * 4608 + o * 18;
        #pragma unroll
        for (int p = 0; p < 18; ++p) { ko[p] = ak[p]; vo[p] = av[p]; }
    }
}

// ===========================================================================
// K2 (rewritten): bf16-MFMA CPB MLP + MFMA sim + softmax + register wAcc.
// grid (2 i-halves, 256 batches) x 256 threads. Chunk = 8 i's = 144 pairs
// = 9 MFMA n-tiles. HT buffer holds h1 then h2 (in-place, wave-own pairs).
// ===========================================================================
__global__ __launch_bounds__(256, 2) void k2_attn(
    const float* __restrict__ q,
    const float* __restrict__ cw1, const float* __restrict__ cb1,
    const float* __restrict__ cw2, const float* __restrict__ cb2,
    const float* __restrict__ cw3, const float* __restrict__ cb3,
    const float* __restrict__ conv_w,
    float* __restrict__ ws)
{
    const int b   = blockIdx.y;
    const int ib0 = blockIdx.x * 156;          // i in [ib0, ib0+156)
    const int tid = threadIdx.x;
    const int w = tid >> 6;                    // wave 0..3
    const int lane = tid & 63;
    const int n = lane & 15, qd = lane >> 4;   // MFMA col / quad

    __shared__ __align__(16) unsigned int HT[144 * 36]; // [pair][72 bf16] (64 used + 8 pad)
    __shared__ __align__(16) float sim_s[2880];         // [i(8)][j(18)][h pad 20]
    __shared__ __align__(16) float k_s[4608];           // [c][j] fp32 (reused as red buf)
    __shared__ __align__(16) float w1_s[128];
    __shared__ __align__(16) float b1_s[64], b2_s[64], b3_s[16];
    __shared__ float n0_s[18], n1_s[18];
    __shared__ unsigned short q_sb[256];                // bf16(q*0.25)

    // ---- stage ----
    q_sb[tid] = f2bf(q[b * 256 + tid] * 0.25f);
    {
        const float* kb = ws + WS_K + (size_t)b * 4608;
        for (int i2 = tid; i2 < 4608; i2 += 256) k_s[i2] = kb[i2];
    }
    if (tid < 128) w1_s[tid] = cw1[tid];
    if (tid < 64) { b1_s[tid] = cb1[tid]; b2_s[tid] = cb2[tid]; }
    if (tid < 16) b3_s[tid] = cb3[tid];
    if (tid < 18) {
        n0_s[tid] = ws[WS_GKV + b * 36 + tid * 2 + 0];
        n1_s[tid] = ws[WS_GKV + b * 36 + tid * 2 + 1];
    }

    // ---- W2/W3 A-fragments (registers, per lane) ----
    short8 W2f[4][2], W3f[2];
    {
        const floatx4* cw2_4 = (const floatx4*)cw2;
        #pragma unroll
        for (int mt = 0; mt < 4; ++mt)
            #pragma unroll
            for (int ks = 0; ks < 2; ++ks) {
                const int base = (mt * 16 + n) * 16 + qd * 2 + ks * 8;
                W2f[mt][ks] = pack8(cw2_4[base], cw2_4[base + 1]);
            }
        const floatx4* cw3_4 = (const floatx4*)cw3;
        #pragma unroll
        for (int ks = 0; ks < 2; ++ks) {
            const int base = n * 16 + qd * 2 + ks * 8;
            W3f[ks] = pack8(cw3_4[base], cw3_4[base + 1]);
        }
    }
    __syncthreads();   // k_s ready

    // ---- sim B-fragments: 4 heads/wave x 2 j-tiles, K padded 16->32 ----
    short8 Bk[4][2];
    #pragma unroll
    for (int hh = 0; hh < 4; ++hh) {
        const int h = w * 4 + hh;
        #pragma unroll
        for (int jt = 0; jt < 2; ++jt) {
            short8 t = {0,0,0,0,0,0,0,0};
            const int j = jt * 16 + n;
            if (qd < 2 && j < 18) {
                #pragma unroll
                for (int e = 0; e < 8; ++e)
                    t[e] = (short)f2bf(k_s[(h * 16 + qd * 8 + e) * 18 + j]);
            }
            Bk[hh][jt] = t;
        }
    }

    float wAcc[18];
    #pragma unroll
    for (int j = 0; j < 18; ++j) wAcc[j] = 0.f;

    // ---- chunk loop: 19 chunks of 8 i's + 1 of 4 ----
    for (int c = 0; c < 20; ++c) {
        const int CI = (c == 19) ? 4 : 8;
        const int NT = (c == 19) ? 5 : 9;
        const int ibase = ib0 + c * 8;

        __syncthreads();   // protect sim_s/HT reuse vs prev chunk consumers

        // --- sim: A-frags from permuted q, MFMA, write [i][j][h] ---
        #pragma unroll
        for (int hh = 0; hh < 4; ++hh) {
            const int h = w * 4 + hh;
            short8 t = {0,0,0,0,0,0,0,0};
            if (qd < 2) {
                #pragma unroll
                for (int e = 0; e < 8; ++e) {
                    const int cc = h * 16 + qd * 8 + e;
                    t[e] = (short)q_sb[(cc * 56 + ibase + n) & 255];
                }
            }
            #pragma unroll
            for (int jt = 0; jt < 2; ++jt) {
                floatx4 D = {0.f, 0.f, 0.f, 0.f};
                D = __builtin_amdgcn_mfma_f32_16x16x32_bf16(t, Bk[hh][jt], D, 0, 0, 0);
                const int j = jt * 16 + n;
                if (qd < 2 && j < 18) {
                    #pragma unroll
                    for (int r = 0; r < 4; ++r) {
                        const int il = qd * 4 + r;
                        if (il < CI) sim_s[(il * 18 + j) * 20 + h] = D[r];
                    }
                }
            }
        }

        // --- h1 -> bf16 -> HT[pair][k] (thread-strided over all pairs) ---
        {
            const int tot = NT * 128;        // pairs * 8 k-groups
            for (int task = tid; task < tot; task += 256) {
                const int p = task >> 3, kg = task & 7;
                const int il = (int)((unsigned)p / 18u);
                const int j = p - il * 18;
                float f0 = 0.f, f1 = 0.f;
                if (il < CI) {
                    const int ii = ibase + il;
                    const int iy = (int)((unsigned)ii / 26u);
                    const int ix = ii - iy * 26;
                    const float gq0 = (float)ix * (2.0f / 11.0f) - 1.0f;
                    const float gq1 = (float)iy * (2.0f / 25.0f) - 1.0f;
                    const float p0 = gq0 - n0_s[j];
                    const float p1 = gq1 - n1_s[j];
                    f0 = copysignf(__logf(1.0f + fabsf(p0)), p0);
                    f1 = copysignf(__logf(1.0f + fabsf(p1)), p1);
                }
                unsigned int ow[4];
                #pragma unroll
                for (int u = 0; u < 4; ++u) {
                    const int k0 = kg * 8 + u * 2;
                    const float ha = fmaxf(fmaf(w1_s[k0*2+0], f0, fmaf(w1_s[k0*2+1], f1, b1_s[k0+0])), 0.f);
                    const float hb = fmaxf(fmaf(w1_s[k0*2+2], f0, fmaf(w1_s[k0*2+3], f1, b1_s[k0+1])), 0.f);
                    ow[u] = (unsigned int)f2bf(ha) | ((unsigned int)f2bf(hb) << 16);
                }
                *((uint4*)&HT[p * 36 + kg * 4]) = make_uint4(ow[0], ow[1], ow[2], ow[3]);
            }
        }
        __syncthreads();   // H1 + sim_s ready

        // --- GEMM2 -> h2 (in place) -> GEMM3 -> logits, wave-own n-tiles ---
        for (int nt = w; nt < NT; nt += 4) {
            const int p = nt * 16 + n;
            const uint4* ht4 = (const uint4*)HT;
            U16 ub0, ub1;
            ub0.u = ht4[p * 9 + qd];            // k = qd*8..+8
            ub1.u = ht4[p * 9 + 4 + qd];        // k = 32 + qd*8..+8
            floatx4 acc[4];
            #pragma unroll
            for (int mt = 0; mt < 4; ++mt) {
                acc[mt] = (floatx4){0.f, 0.f, 0.f, 0.f};
                acc[mt] = __builtin_amdgcn_mfma_f32_16x16x32_bf16(W2f[mt][0], ub0.s, acc[mt], 0, 0, 0);
                acc[mt] = __builtin_amdgcn_mfma_f32_16x16x32_bf16(W2f[mt][1], ub1.s, acc[mt], 0, 0, 0);
            }
            const floatx4* b2_4 = (const floatx4*)b2_s;
            #pragma unroll
            for (int mt = 0; mt < 4; ++mt) {
                const floatx4 bb = b2_4[mt * 4 + qd];
                const unsigned int u0 = (unsigned int)f2bf(fmaxf(acc[mt][0] + bb[0], 0.f))
                                      | ((unsigned int)f2bf(fmaxf(acc[mt][1] + bb[1], 0.f)) << 16);
                const unsigned int u1 = (unsigned int)f2bf(fmaxf(acc[mt][2] + bb[2], 0.f))
                                      | ((unsigned int)f2bf(fmaxf(acc[mt][3] + bb[3], 0.f)) << 16);
                *((uint2*)&HT[p * 36 + mt * 8 + qd * 2]) = make_uint2(u0, u1);
            }
            U16 uc0, uc1;
            uc0.u = ht4[p * 9 + qd];
            uc1.u = ht4[p * 9 + 4 + qd];
            floatx4 a3 = {0.f, 0.f, 0.f, 0.f};
            a3 = __builtin_amdgcn_mfma_f32_16x16x32_bf16(W3f[0], uc0.s, a3, 0, 0, 0);
            a3 = __builtin_amdgcn_mfma_f32_16x16x32_bf16(W3f[1], uc1.s, a3, 0, 0, 0);
            if (p < CI * 18) {
                const int il = (int)((unsigned)p / 18u);
                const int j = p - il * 18;
                floatx4* sp = (floatx4*)&sim_s[(il * 18 + j) * 20 + qd * 4];
                const floatx4 sv = *sp;
                const floatx4 b3v = ((const floatx4*)b3_s)[qd];
                floatx4 lg;
                #pragma unroll
                for (int r = 0; r < 4; ++r) lg[r] = a3[r] + b3v[r] + sv[r];
                *sp = lg;   // logits in place
            }
        }
        __syncthreads();   // logits ready

        // --- softmax over j + conv-weighted accumulation into registers ---
        if (tid < 128) {
            const int il = tid >> 4, h = tid & 15;
            if (il < CI) {
                float lv[18];
                #pragma unroll
                for (int j = 0; j < 18; ++j) lv[j] = sim_s[(il * 18 + j) * 20 + h];
                float m = lv[0];
                #pragma unroll
                for (int j = 1; j < 18; ++j) m = fmaxf(m, lv[j]);
                float s = 0.f;
                #pragma unroll
                for (int j = 0; j < 18; ++j) { lv[j] = __expf(lv[j] - m); s += lv[j]; }
                const float wgt = conv_w[ibase + il] / s;
                #pragma unroll
                for (int j = 0; j < 18; ++j) wAcc[j] = fmaf(wgt, lv[j], wAcc[j]);
            }
        }
    }

    // ---- reduce wAcc over the 8 i-slots, one atomicAdd set per block ----
    __syncthreads();
    if (tid < 128) {
        const int il = tid >> 4, h = tid & 15;
        #pragma unroll
        for (int j = 0; j < 18; ++j) k_s[il * 288 + h * 18 + j] = wAcc[j];
    }
    __syncthreads();
    for (int idx = tid; idx < 288; idx += 256) {
        float s = 0.f;
        #pragma unroll
        for (int sl = 0; sl < 8; ++sl) s += k_s[sl * 288 + idx];
        atomicAdd(&ws[WS_WA + b * 288 + idx], s);
    }
}

// ===========================================================================
// K3: m = wA . v ; pooled = w_out.m + b_out*S + conv_b ; +q ; LayerNorm
// (unchanged from round 1)
// ===========================================================================
__global__ __launch_bounds__(256) void k3_final(
    const float* __restrict__ q,
    const float* __restrict__ w_out, const float* __restrict__ b_out,
    const float* __restrict__ conv_w, const float* __restrict__ conv_b,
    const float* __restrict__ ln_g, const float* __restrict__ ln_b,
    const float* __restrict__ ws, float* __restrict__ out)
{
    const int b = blockIdx.x, tid = threadIdx.x;
    __shared__ float wA_s[288];
    __shared__ float m_s[256];
    __shared__ float redS[4], redA[4], redB[4];

    for (int i = tid; i < 288; i += 256) wA_s[i] = ws[WS_WA + b * 288 + i];
    __syncthreads();

    {
        const int c = tid;
        const float* vr = ws + WS_V + (size_t)b * 4608 + c * 18;
        const float* wr = &wA_s[(c >> 4) * 18];
        float acc = 0.f;
        #pragma unroll
        for (int j = 0; j < 18; ++j) acc += wr[j] * vr[j];
        m_s[c] = acc;
    }
    {
        float sp = conv_w[tid] + ((tid + 256) < 312 ? conv_w[tid + 256] : 0.f);
        for (int d = 32; d > 0; d >>= 1) sp += __shfl_down(sp, d, 64);
        if ((tid & 63) == 0) redS[tid >> 6] = sp;
    }
    __syncthreads();
    const float S = redS[0] + redS[1] + redS[2] + redS[3];

    const int o = tid;
    float acc = b_out[o] * S + conv_b[0];
    const float4* wor = (const float4*)(w_out + o * 256);
    const float4* m4 = (const float4*)m_s;
    for (int c4 = 0; c4 < 64; ++c4) {
        const float4 wq = wor[c4];
        const float4 mq = m4[c4];
        acc += wq.x * mq.x + wq.y * mq.y + wq.z * mq.z + wq.w * mq.w;
    }
    const float y = acc + q[b * 256 + o];

    float s1 = y, s2 = y * y;
    for (int d = 32; d > 0; d >>= 1) {
        s1 += __shfl_down(s1, d, 64);
        s2 += __shfl_down(s2, d, 64);
    }
    if ((tid & 63) == 0) { redA[tid >> 6] = s1; redB[tid >> 6] = s2; }
    __syncthreads();
    const float S1 = redA[0] + redA[1] + redA[2] + redA[3];
    const float S2 = redB[0] + redB[1] + redB[2] + redB[3];
    const float mu = S1 * (1.0f / 256.0f);
    const float var = S2 * (1.0f / 256.0f) - mu * mu;
    out[b * 256 + o] = (y - mu) * rsqrtf(var + 1e-5f) * ln_g[o] + ln_b[o];
}

// ===========================================================================
extern "C" void kernel_launch(void* const* d_in, const int* in_sizes, int n_in,
                              void* d_out, int out_size, void* d_ws, size_t ws_size,
                              hipStream_t stream) {
    const float* x       = (const float*)d_in[0];
    const float* q       = (const float*)d_in[1];
    const float* w_dw    = (const float*)d_in[2];
    const float* b_dw    = (const float*)d_in[3];
    const float* w_pw    = (const float*)d_in[4];
    const float* wk      = (const float*)d_in[5];
    const float* wv      = (const float*)d_in[6];
    const float* w_out   = (const float*)d_in[7];
    const float* b_out   = (const float*)d_in[8];
    const float* cw1     = (const float*)d_in[9];
    const float* cb1     = (const float*)d_in[10];
    const float* cw2     = (const float*)d_in[11];
    const float* cb2     = (const float*)d_in[12];
    const float* cw3     = (const float*)d_in[13];
    const float* cb3     = (const float*)d_in[14];
    const float* conv_w  = (const float*)d_in[15];
    const float* conv_b  = (const float*)d_in[16];
    const float* ln_g    = (const float*)d_in[17];
    const float* ln_b    = (const float*)d_in[18];
    float* ws = (float*)d_ws;
    float* out = (float*)d_out;

    hipMemsetAsync((char*)d_ws + (size_t)WS_WA * sizeof(float), 0, WS_WA_BYTES, stream);
    k1_prep<<<256, 256, 0, stream>>>(x, q, w_dw, b_dw, w_pw, wk, wv, ws);
    k2_attn<<<dim3(2, 256), 256, 0, stream>>>(q, cw1, cb1, cw2, cb2, cw3, cb3, conv_w, ws);
    k3_final<<<256, 256, 0, stream>>>(q, w_out, b_out, conv_w, conv_b, ln_g, ln_b, ws, out);
}

// Round 3
// 268.092 us; speedup vs baseline: 3.3276x; 1.2624x over previous
//
#include <hip/hip_runtime.h>
#include <math.h>

// ---------------------------------------------------------------------------
// DIM=256 HEADS=16 DHEAD=16 H=12 W=26 (HW=312)  Hk=3 Wk=6 (J=18)  B=256
// q_map[b,c,s] = q[b,(c*56+s)&255]
// Fused single-kernel design: grid 256 (one block per batch) x 512 threads.
// d_ws holds pre-packed bf16 MFMA A-fragments (setup kernel k0_setup).
// ---------------------------------------------------------------------------

typedef __attribute__((ext_vector_type(8))) short short8;   // 8 bf16
typedef __attribute__((ext_vector_type(4))) float floatx4;

union U16 { uint4 u; short8 s; };

__device__ __forceinline__ unsigned int f2bf(float f) {   // RNE f32->bf16 (low 16)
    unsigned int u = __float_as_uint(f);
    u += 0x7fffu + ((u >> 16) & 1u);
    return u >> 16;
}
__device__ __forceinline__ unsigned int pk2(float a, float b) {
    return f2bf(a) | (f2bf(b) << 16);
}
__device__ __forceinline__ float bf2f(unsigned short v) {
    return __uint_as_float((unsigned int)v << 16);
}

// d_ws layout: uint4-indexed frag tables then float wdwT
#define WSF_W2 16384            // uint4 index
#define WSF_W3 16896            // uint4 index
#define WSF_DW 68096            // float index: wdwT[36][256]

// ===========================================================================
// k0_setup: pre-pack weights into MFMA-fragment-linear layouts (runs every
// call; d_ws is re-poisoned by the harness each launch).
//   wk/wv frags: entry id = m2*8192 + mt*512 + ks*64 + lane  -> uint4 (8 bf16)
//                A[m = mt*16 + (lane&15)][k = ks*32 + (lane>>4)*8 + e]
//   w2F: 16384 + mt*128 + ks*64 + lane ; w3F: 16896 + ks*64 + lane
//   wdwT[i*256 + c] = w_dw[c*36 + i]
// ===========================================================================
__global__ __launch_bounds__(256) void k0_setup(
    const float* __restrict__ wk, const float* __restrict__ wv,
    const float* __restrict__ cw2, const float* __restrict__ cw3,
    const float* __restrict__ w_dw, unsigned int* __restrict__ ws)
{
    const int t = blockIdx.x * 256 + threadIdx.x;   // 16384 threads
    uint4* ws4 = (uint4*)ws;
    {
        const int m2 = t >> 13;
        const int r = t & 8191;
        const int mt = r >> 9, ks = (r >> 6) & 7, lane = r & 63;
        const int nn = lane & 15, qd = lane >> 4;
        const float* src = (m2 ? wv : wk) + (mt * 16 + nn) * 256 + ks * 32 + qd * 8;
        uint4 o;
        o.x = pk2(src[0], src[1]); o.y = pk2(src[2], src[3]);
        o.z = pk2(src[4], src[5]); o.w = pk2(src[6], src[7]);
        ws4[t] = o;
    }
    if (t < 512) {
        const int mt = t >> 7, ks = (t >> 6) & 1, lane = t & 63;
        const int nn = lane & 15, qd = lane >> 4;
        const float* src = cw2 + (mt * 16 + nn) * 64 + ks * 32 + qd * 8;
        uint4 o;
        o.x = pk2(src[0], src[1]); o.y = pk2(src[2], src[3]);
        o.z = pk2(src[4], src[5]); o.w = pk2(src[6], src[7]);
        ws4[WSF_W2 + t] = o;
    }
    if (t < 128) {
        const int ks = t >> 6, lane = t & 63;
        const int nn = lane & 15, qd = lane >> 4;
        const float* src = cw3 + nn * 64 + ks * 32 + qd * 8;
        uint4 o;
        o.x = pk2(src[0], src[1]); o.y = pk2(src[2], src[3]);
        o.z = pk2(src[4], src[5]); o.w = pk2(src[6], src[7]);
        ws4[WSF_W3 + t] = o;
    }
    float* wsf = (float*)ws;
    for (int k = t; k < 9216; k += 16384) {
        const int c = k / 36, i = k - c * 36;
        wsf[WSF_DW + i * 256 + c] = w_dw[k];
    }
}

// ===========================================================================
// k_fused: whole forward for one batch element per block.
// ===========================================================================
__global__ __launch_bounds__(512, 2) void k_fused(
    const float* __restrict__ x, const float* __restrict__ q,
    const float* __restrict__ b_dw, const float* __restrict__ w_pw,
    const float* __restrict__ cw1, const float* __restrict__ cb1,
    const float* __restrict__ cb2, const float* __restrict__ cb3,
    const float* __restrict__ conv_w, const float* __restrict__ conv_b,
    const float* __restrict__ w_out, const float* __restrict__ b_out,
    const float* __restrict__ ln_g, const float* __restrict__ ln_b,
    const unsigned int* __restrict__ ws, float* __restrict__ out)
{
    const int b = blockIdx.x, tid = threadIdx.x;
    const int w = tid >> 6, lane = tid & 63;
    const int n = lane & 15, qd = lane >> 4;

    // ---- persistent LDS (19.6 KB) ----
    __shared__ float qf_s[256];
    __shared__ unsigned short q_sb[256];            // bf16(q*0.25)
    __shared__ unsigned short v_sb[5120];           // v bf16 [256][20]
    __shared__ float F0[468], F1[216];              // log tables [26][18], [12][18]
    __shared__ unsigned int lutxy[312];             // ix | iy<<16
    __shared__ float off_s[36], n0_s[18], n1_s[18];
    __shared__ float sx0[18], sy0[18], swx[18], swy[18];
    __shared__ float wA_s[288];
    __shared__ __align__(16) float m_s[256];
    __shared__ float pooled_s[256], redb[16];
    // ---- union region (38.5 KB) ----
    __shared__ __align__(16) unsigned char UB[38464];
    float* S_ = (float*)UB;                          // [16 il][18 j][17 h] 19584B (phase B)
    unsigned short* kvT = (unsigned short*)UB;       // [18 j][264 c] bf16 (sampling/proj)
    float* qsw = (float*)UB;                         // 16 copies x 258 (conv)
    float* t_s = (float*)(UB + 16512);               // [18 p][256 c] (conv/offsets)
    unsigned short* k_sb = (unsigned short*)(UB + 20000);  // k bf16 [256][20] (proj->Bk)
    unsigned int* h2w = (unsigned int*)(UB + 20000); // per-wave h2 scratch [8][16][36]

    const uint4* ws4 = (const uint4*)ws;
    const float* wsf = (const float*)ws;

    // ---- per-lane constant registers (global loads, no LDS deps) ----
    uint4 W2f[4][2], W3f[2];
    #pragma unroll
    for (int mtl = 0; mtl < 4; ++mtl)
        #pragma unroll
        for (int ks = 0; ks < 2; ++ks)
            W2f[mtl][ks] = ws4[WSF_W2 + mtl * 128 + ks * 64 + lane];
    W3f[0] = ws4[WSF_W3 + lane];
    W3f[1] = ws4[WSF_W3 + 64 + lane];

    float W1a[16], W1b[16], B1r[16];
    #pragma unroll
    for (int kk = 0; kk < 16; ++kk) {
        const int kid = (kk < 8) ? (qd * 8 + kk) : (32 + qd * 8 + kk - 8);
        W1a[kk] = cw1[kid * 2]; W1b[kk] = cw1[kid * 2 + 1]; B1r[kk] = cb1[kid];
    }
    float bb2[16];
    #pragma unroll
    for (int mtl = 0; mtl < 4; ++mtl)
        #pragma unroll
        for (int r = 0; r < 4; ++r) bb2[mtl * 4 + r] = cb2[mtl * 16 + qd * 4 + r];
    float bb3[4];
    #pragma unroll
    for (int r = 0; r < 4; ++r) bb3[r] = cb3[qd * 4 + r];

    // ---- stage 0: q, swizzled q copies, ix/iy lut ----
    if (tid < 256) {
        const float qv = q[b * 256 + tid];
        qf_s[tid] = qv;
        q_sb[tid] = (unsigned short)f2bf(qv * 0.25f);
    }
    for (int u = tid; u < 4128; u += 512) {
        const int r = u / 258, i = u - r * 258;
        qsw[u] = (i < 256) ? q[b * 256 + i] : 0.f;
    }
    for (int u = tid; u < 312; u += 512) {
        const int iy = u / 26;
        lutxy[u] = (unsigned int)(u - iy * 26) | ((unsigned int)iy << 16);
    }
    __syncthreads();

    // ---- depthwise conv 6x6 s4 p1 + GELU -> t_s ----
    {
        const int c = tid & 255, g = tid >> 8;     // g: jw-half (wave-uniform)
        float wreg[36];
        #pragma unroll
        for (int i = 0; i < 36; ++i) wreg[i] = wsf[WSF_DW + i * 256 + c];
        float acc[9];
        const float bv = b_dw[c];
        #pragma unroll
        for (int a = 0; a < 9; ++a) acc[a] = bv;
        const int cb = (c * 56) & 255;
        const int cp = (c & 15) * 258;
        for (int jh = 0; jh < 3; ++jh) {
            for (int kh = 0; kh < 6; ++kh) {
                const int ih = jh * 4 - 1 + kh;
                if (ih < 0 || ih >= 12) continue;
                const int rb = ih * 26;
                #pragma unroll
                for (int jwl = 0; jwl < 3; ++jwl) {
                    const int jw = g * 3 + jwl;
                    #pragma unroll
                    for (int kw = 0; kw < 6; ++kw) {
                        const int iw = jw * 4 - 1 + kw;
                        if (iw < 0 || iw >= 26) continue;
                        acc[jh * 3 + jwl] += wreg[kh * 6 + kw] * qsw[cp + ((cb + rb + iw) & 255)];
                    }
                }
            }
        }
        #pragma unroll
        for (int a = 0; a < 9; ++a) {
            const int jh = a / 3, jwl = a - jh * 3;
            const int p = jh * 6 + g * 3 + jwl;
            const float v = acc[a];
            t_s[p * 256 + c] = 0.5f * v * (1.0f + erff(v * 0.70710678118654752f));
        }
    }
    __syncthreads();

    // ---- offsets: 36 dots over 256 channels ----
    for (int oi = w; oi < 36; oi += 8) {
        const int o = oi / 18, p = oi - o * 18;
        float s = 0.f;
        for (int c = lane; c < 256; c += 64) s += w_pw[o * 256 + c] * t_s[p * 256 + c];
        for (int d = 32; d > 0; d >>= 1) s += __shfl_down(s, d, 64);
        if (lane == 0) off_s[oi] = 4.0f * tanhf(s);
    }
    __syncthreads();

    // ---- grid coords + bilinear params ----
    if (tid < 18) {
        const int j = tid, jh = j / 6, jw = j - jh * 6;
        const float vg0 = (float)jw + off_s[j];
        const float vg1 = (float)jh + off_s[18 + j];
        const float n0 = 2.0f * vg0 / 2.0f - 1.0f;
        const float n1 = 2.0f * vg1 / 5.0f - 1.0f;
        n0_s[j] = n0; n1_s[j] = n1;
        const float xp = ((n0 + 1.0f) * 26.0f - 1.0f) * 0.5f;
        const float yp = ((n1 + 1.0f) * 12.0f - 1.0f) * 0.5f;
        const float x0 = floorf(xp), y0 = floorf(yp);
        sx0[j] = x0; sy0[j] = y0; swx[j] = xp - x0; swy[j] = yp - y0;
    }
    __syncthreads();

    // ---- bilinear sample -> kvT bf16 [j][264]; build F0/F1 log tables ----
    {
        const int c = tid & 255, g = tid >> 8;
        const float* xb = x + ((size_t)b * 256 + c) * 312;
        for (int jj = 0; jj < 9; ++jj) {
            const int j = g * 9 + jj;
            const int x0 = (int)sx0[j], y0 = (int)sy0[j];
            const int x1 = x0 + 1, y1 = y0 + 1;
            const float wx1 = swx[j], wy1 = swy[j];
            const float wx0 = 1.f - wx1, wy0 = 1.f - wy1;
            const bool xv0 = (x0 >= 0) & (x0 < 26), xv1 = (x1 >= 0) & (x1 < 26);
            const bool yv0 = (y0 >= 0) & (y0 < 12), yv1 = (y1 >= 0) & (y1 < 12);
            const float v00 = (xv0 & yv0) ? xb[y0 * 26 + x0] : 0.f;
            const float v01 = (xv1 & yv0) ? xb[y0 * 26 + x1] : 0.f;
            const float v10 = (xv0 & yv1) ? xb[y1 * 26 + x0] : 0.f;
            const float v11 = (xv1 & yv1) ? xb[y1 * 26 + x1] : 0.f;
            const float val = wy0 * (wx0 * v00 + wx1 * v01) + wy1 * (wx0 * v10 + wx1 * v11);
            kvT[j * 264 + c] = (unsigned short)f2bf(val);
        }
    }
    for (int u = tid; u < 684; u += 512) {
        if (u < 468) {
            const int ixv = u / 18, j = u - ixv * 18;
            const float p0 = (float)ixv * (2.0f / 11.0f) - 1.0f - n0_s[j];
            F0[u] = copysignf(__logf(1.0f + fabsf(p0)), p0);
        } else {
            const int u2 = u - 468;
            const int iyv = u2 / 18, j = u2 - iyv * 18;
            const float p1 = (float)iyv * (2.0f / 25.0f) - 1.0f - n1_s[j];
            F1[u2] = copysignf(__logf(1.0f + fabsf(p1)), p1);
        }
    }
    __syncthreads();

    // ---- k/v projection via MFMA: wave w -> matrix (w&1), m-tiles (w>>1)+4l ----
    {
        const int m2 = w & 1, mtb = w >> 1;
        floatx4 pa[4][2];
        #pragma unroll
        for (int a = 0; a < 4; ++a) {
            pa[a][0] = (floatx4){0.f, 0.f, 0.f, 0.f};
            pa[a][1] = (floatx4){0.f, 0.f, 0.f, 0.f};
        }
        for (int ks = 0; ks < 8; ++ks) {
            U16 b0, b1;
            b0.u = *(const uint4*)(kvT + n * 264 + ks * 32 + qd * 8);
            b1.u = make_uint4(0u, 0u, 0u, 0u);
            if (n < 2) b1.u = *(const uint4*)(kvT + (16 + n) * 264 + ks * 32 + qd * 8);
            #pragma unroll
            for (int mtl = 0; mtl < 4; ++mtl) {
                const int mt = mtb + mtl * 4;
                U16 A; A.u = ws4[m2 * 8192 + mt * 512 + ks * 64 + lane];
                pa[mtl][0] = __builtin_amdgcn_mfma_f32_16x16x32_bf16(A.s, b0.s, pa[mtl][0], 0, 0, 0);
                pa[mtl][1] = __builtin_amdgcn_mfma_f32_16x16x32_bf16(A.s, b1.s, pa[mtl][1], 0, 0, 0);
            }
        }
        unsigned short* dst = m2 ? v_sb : k_sb;
        #pragma unroll
        for (int mtl = 0; mtl < 4; ++mtl) {
            const int mt = mtb + mtl * 4;
            #pragma unroll
            for (int r = 0; r < 4; ++r) {
                const int o = mt * 16 + qd * 4 + r;
                dst[o * 20 + n] = (unsigned short)f2bf(pa[mtl][0][r]);
                if (n < 2) dst[o * 20 + 16 + n] = (unsigned short)f2bf(pa[mtl][1][r]);
            }
        }
    }
    __syncthreads();

    // ---- Bk fragments for sim (wave w: heads 2w, 2w+1) ----
    uint4 BkU[2][2];
    #pragma unroll
    for (int hh = 0; hh < 2; ++hh)
        #pragma unroll
        for (int jt = 0; jt < 2; ++jt) {
            unsigned int u0 = 0, u1 = 0, u2 = 0, u3 = 0;
            if (qd < 2 && (jt == 0 || n < 2)) {
                const int h = w * 2 + hh;
                const int j = jt * 16 + n;
                const int cb0 = (h * 16 + qd * 8) * 20 + j;
                u0 = (unsigned)k_sb[cb0] | ((unsigned)k_sb[cb0 + 20] << 16);
                u1 = (unsigned)k_sb[cb0 + 40] | ((unsigned)k_sb[cb0 + 60] << 16);
                u2 = (unsigned)k_sb[cb0 + 80] | ((unsigned)k_sb[cb0 + 100] << 16);
                u3 = (unsigned)k_sb[cb0 + 120] | ((unsigned)k_sb[cb0 + 140] << 16);
            }
            BkU[hh][jt] = make_uint4(u0, u1, u2, u3);
        }
    __syncthreads();   // k_sb dead; h2w region live from here

    // ---- chunk loop: 20 chunks of 16 i's ----
    float wAcc[18];
    #pragma unroll
    for (int j = 0; j < 18; ++j) wAcc[j] = 0.f;

    for (int ch = 0; ch < 20; ++ch) {
        const int ibase = ch * 16;
        const int CI = (ch == 19) ? 8 : 16;

        // (a) sim: per wave 2 heads x 2 j-tiles -> S_[il][j][h]
        #pragma unroll
        for (int hh = 0; hh < 2; ++hh) {
            const int h = w * 2 + hh;
            unsigned int a0 = 0, a1 = 0, a2 = 0, a3u = 0;
            if (qd < 2) {
                const int base = h * 16 + qd * 8;
                a0 = (unsigned)q_sb[((base + 0) * 56 + ibase + n) & 255] |
                     ((unsigned)q_sb[((base + 1) * 56 + ibase + n) & 255] << 16);
                a1 = (unsigned)q_sb[((base + 2) * 56 + ibase + n) & 255] |
                     ((unsigned)q_sb[((base + 3) * 56 + ibase + n) & 255] << 16);
                a2 = (unsigned)q_sb[((base + 4) * 56 + ibase + n) & 255] |
                     ((unsigned)q_sb[((base + 5) * 56 + ibase + n) & 255] << 16);
                a3u = (unsigned)q_sb[((base + 6) * 56 + ibase + n) & 255] |
                      ((unsigned)q_sb[((base + 7) * 56 + ibase + n) & 255] << 16);
            }
            U16 Af; Af.u = make_uint4(a0, a1, a2, a3u);
            #pragma unroll
            for (int jt = 0; jt < 2; ++jt) {
                U16 Bf; Bf.u = BkU[hh][jt];
                floatx4 D = {0.f, 0.f, 0.f, 0.f};
                D = __builtin_amdgcn_mfma_f32_16x16x32_bf16(Af.s, Bf.s, D, 0, 0, 0);
                const int j = jt * 16 + n;
                if (j < 18) {
                    #pragma unroll
                    for (int r = 0; r < 4; ++r)
                        S_[((qd * 4 + r) * 18 + j) * 17 + h] = D[r];
                }
            }
        }
        __syncthreads();

        // (b) CPB MLP + logits, n-tile = one j; lanes n = il
        {
            const int i0 = ibase + n;
            const unsigned int lv = lutxy[i0 < 312 ? i0 : 311];
            const int ix = (int)(lv & 0xffffu), iy = (int)(lv >> 16);
            for (int nt = w; nt < 18; nt += 8) {
                const float f0 = F0[ix * 18 + nt];
                const float f1 = F1[iy * 18 + nt];
                float h1v[16];
                #pragma unroll
                for (int kk = 0; kk < 16; ++kk)
                    h1v[kk] = fmaxf(fmaf(W1a[kk], f0, fmaf(W1b[kk], f1, B1r[kk])), 0.f);
                U16 ub0, ub1;
                ub0.u = make_uint4(pk2(h1v[0], h1v[1]), pk2(h1v[2], h1v[3]),
                                   pk2(h1v[4], h1v[5]), pk2(h1v[6], h1v[7]));
                ub1.u = make_uint4(pk2(h1v[8], h1v[9]), pk2(h1v[10], h1v[11]),
                                   pk2(h1v[12], h1v[13]), pk2(h1v[14], h1v[15]));
                floatx4 g2[4];
                #pragma unroll
                for (int mtl = 0; mtl < 4; ++mtl) {
                    U16 A0; A0.u = W2f[mtl][0];
                    U16 A1; A1.u = W2f[mtl][1];
                    floatx4 acc = {0.f, 0.f, 0.f, 0.f};
                    acc = __builtin_amdgcn_mfma_f32_16x16x32_bf16(A0.s, ub0.s, acc, 0, 0, 0);
                    acc = __builtin_amdgcn_mfma_f32_16x16x32_bf16(A1.s, ub1.s, acc, 0, 0, 0);
                    g2[mtl] = acc;
                }
                unsigned int* hw = h2w + w * 576 + n * 36;
                #pragma unroll
                for (int mtl = 0; mtl < 4; ++mtl) {
                    const float e0 = fmaxf(g2[mtl][0] + bb2[mtl * 4 + 0], 0.f);
                    const float e1 = fmaxf(g2[mtl][1] + bb2[mtl * 4 + 1], 0.f);
                    const float e2 = fmaxf(g2[mtl][2] + bb2[mtl * 4 + 2], 0.f);
                    const float e3 = fmaxf(g2[mtl][3] + bb2[mtl * 4 + 3], 0.f);
                    hw[mtl * 8 + qd * 2]     = pk2(e0, e1);
                    hw[mtl * 8 + qd * 2 + 1] = pk2(e2, e3);
                }
                U16 uc0, uc1;
                uc0.u = *(const uint4*)(hw + qd * 4);
                uc1.u = *(const uint4*)(hw + 16 + qd * 4);
                floatx4 a3 = {0.f, 0.f, 0.f, 0.f};
                {
                    U16 A0; A0.u = W3f[0]; U16 A1; A1.u = W3f[1];
                    a3 = __builtin_amdgcn_mfma_f32_16x16x32_bf16(A0.s, uc0.s, a3, 0, 0, 0);
                    a3 = __builtin_amdgcn_mfma_f32_16x16x32_bf16(A1.s, uc1.s, a3, 0, 0, 0);
                }
                float* sp = S_ + (n * 18 + nt) * 17 + qd * 4;
                #pragma unroll
                for (int r = 0; r < 4; ++r) sp[r] = a3[r] + bb3[r] + sp[r];
            }
        }
        __syncthreads();

        // (c) softmax over j + conv-weighted accumulation (256 threads)
        if (tid < 256) {
            const int il = tid >> 4, h = tid & 15;
            if (il < CI) {
                float lv[18];
                #pragma unroll
                for (int j = 0; j < 18; ++j) lv[j] = S_[(il * 18 + j) * 17 + h];
                float m = lv[0];
                #pragma unroll
                for (int j = 1; j < 18; ++j) m = fmaxf(m, lv[j]);
                float s = 0.f;
                #pragma unroll
                for (int j = 0; j < 18; ++j) { lv[j] = __expf(lv[j] - m); s += lv[j]; }
                const float wgt = conv_w[ibase + il] / s;
                #pragma unroll
                for (int j = 0; j < 18; ++j) wAcc[j] = fmaf(wgt, lv[j], wAcc[j]);
            }
        }
        __syncthreads();
    }

    // ---- reduce wAcc over il-slots -> wA_s[h][j] ----
    if (tid < 256) {
        const int il = tid >> 4, h = tid & 15;
        float* wred = (float*)UB;
        #pragma unroll
        for (int j = 0; j < 18; ++j) wred[(il * 16 + h) * 18 + j] = wAcc[j];
    }
    __syncthreads();
    {
        const float* wred = (const float*)UB;
        for (int u = tid; u < 288; u += 512) {
            const int h = u / 18, j = u - h * 18;
            float s = 0.f;
            #pragma unroll
            for (int il = 0; il < 16; ++il) s += wred[(il * 16 + h) * 18 + j];
            wA_s[u] = s;
        }
    }
    // conv_w total (per-wave partials)
    {
        float v = 0.f;
        for (int u = tid; u < 312; u += 512) v += conv_w[u];
        for (int d = 32; d > 0; d >>= 1) v += __shfl_down(v, d, 64);
        if (lane == 0) redb[w] = v;
    }
    __syncthreads();

    // ---- m[c] = sum_j wA[h][j] * v[c][j] ----
    if (tid < 256) {
        const int c = tid;
        const int hb = (c >> 4) * 18;
        float acc = 0.f;
        #pragma unroll
        for (int j = 0; j < 18; ++j) acc += wA_s[hb + j] * bf2f(v_sb[c * 20 + j]);
        m_s[c] = acc;
    }
    __syncthreads();

    const float Ssum = redb[0] + redb[1] + redb[2] + redb[3] +
                       redb[4] + redb[5] + redb[6] + redb[7];

    // ---- pooled = w_out . m  (wave-cooperative coalesced GEMV) ----
    {
        const float4 mm = *(const float4*)(m_s + lane * 4);
        for (int ol = 0; ol < 32; ++ol) {
            const int o = w * 32 + ol;
            const float4 wq = *(const float4*)(w_out + o * 256 + lane * 4);
            float d = wq.x * mm.x + wq.y * mm.y + wq.z * mm.z + wq.w * mm.w;
            for (int dd = 32; dd > 0; dd >>= 1) d += __shfl_down(d, dd, 64);
            if (lane == 0) pooled_s[o] = d;
        }
    }
    __syncthreads();

    // ---- residual + LayerNorm ----
    if (tid < 256) {
        const int o = tid;
        const float y = pooled_s[o] + b_out[o] * Ssum + conv_b[0] + qf_s[o];
        float s1 = y, s2 = y * y;
        for (int d = 32; d > 0; d >>= 1) { s1 += __shfl_down(s1, d, 64); s2 += __shfl_down(s2, d, 64); }
        if (lane == 0) { redb[8 + w] = s1; redb[12 + w] = s2; }
    }
    __syncthreads();
    if (tid < 256) {
        const int o = tid;
        const float y = pooled_s[o] + b_out[o] * Ssum + conv_b[0] + qf_s[o];
        const float S1 = redb[8] + redb[9] + redb[10] + redb[11];
        const float S2 = redb[12] + redb[13] + redb[14] + redb[15];
        const float mu = S1 * (1.0f / 256.0f);
        const float var = S2 * (1.0f / 256.0f) - mu * mu;
        out[b * 256 + o] = (y - mu) * rsqrtf(var + 1e-5f) * ln_g[o] + ln_b[o];
    }
}

// ===========================================================================
extern "C" void kernel_launch(void* const* d_in, const int* in_sizes, int n_in,
                              void* d_out, int out_size, void* d_ws, size_t ws_size,
                              hipStream_t stream) {
    const float* x       = (const float*)d_in[0];
    const float* q       = (const float*)d_in[1];
    const float* w_dw    = (const float*)d_in[2];
    const float* b_dwp   = (const float*)d_in[3];
    const float* w_pw    = (const float*)d_in[4];
    const float* wk      = (const float*)d_in[5];
    const float* wv      = (const float*)d_in[6];
    const float* w_out   = (const float*)d_in[7];
    const float* b_out   = (const float*)d_in[8];
    const float* cw1     = (const float*)d_in[9];
    const float* cb1     = (const float*)d_in[10];
    const float* cw2     = (const float*)d_in[11];
    const float* cb2     = (const float*)d_in[12];
    const float* cw3     = (const float*)d_in[13];
    const float* cb3     = (const float*)d_in[14];
    const float* conv_w  = (const float*)d_in[15];
    const float* conv_b  = (const float*)d_in[16];
    const float* ln_g    = (const float*)d_in[17];
    const float* ln_b    = (const float*)d_in[18];
    float* out = (float*)d_out;
    unsigned int* ws = (unsigned int*)d_ws;

    k0_setup<<<64, 256, 0, stream>>>(wk, wv, cw2, cw3, w_dw, ws);
    k_fused<<<256, 512, 0, stream>>>(x, q, b_dwp, w_pw, cw1, cb1, cb2, cb3,
                                     conv_w, conv_b, w_out, b_out, ln_g, ln_b,
                                     (const unsigned int*)ws, out);
}